// Round 1
// baseline (166.706 us; speedup 1.0000x reference)
//
#include <hip/hip_runtime.h>
#include <math.h>

// SSIM loss, fused single-pass:
//   5 depthwise 11x11 Gaussian blurs (separable) + SSIM map + global mean.
// Input: image, target fp32 [16,3,512,512]. Output: 1 scalar fp32.

#define HH 512
#define WW 512
#define NPLANES 48            // 16*3
#define TW 64                 // tile width  (output)
#define TH 32                 // tile height (output)
#define RAD 5
#define IW (TW + 2*RAD)       // 74
#define IH (TH + 2*RAD)       // 42
#define SSTRIDE 76            // padded LDS row stride for raw tiles
#define KW 11

struct GaussW { float g[KW]; };

__global__ void ssim_init_out(float* out) { out[0] = 1.0f; }

__global__ __launch_bounds__(256, 2)
void ssim_fused(const float* __restrict__ img, const float* __restrict__ tgt,
                float* __restrict__ out, GaussW gw) {
    __shared__ float sx[IH * SSTRIDE];
    __shared__ float sy[IH * SSTRIDE];
    __shared__ float hb[5 * IH * TW];

    const int tid = threadIdx.x;
    const int p  = blockIdx.z;
    const int r0 = blockIdx.y * TH - RAD;
    const int c0 = blockIdx.x * TW - RAD;
    const float* ip = img + (size_t)p * (HH * WW);
    const float* tp = tgt + (size_t)p * (HH * WW);

    // ---- Stage A: stage halo region of both inputs into LDS (zero-pad) ----
    for (int i = tid; i < IH * IW; i += 256) {
        int r = i / IW;
        int c = i - r * IW;
        int gr = r0 + r, gc = c0 + c;
        float vx = 0.f, vy = 0.f;
        if (gr >= 0 && gr < HH && gc >= 0 && gc < WW) {
            int gi = gr * WW + gc;
            vx = ip[gi];
            vy = tp[gi];
        }
        sx[r * SSTRIDE + c] = vx;
        sy[r * SSTRIDE + c] = vy;
    }
    __syncthreads();

    // ---- Stage B: horizontal blur of {x, y, x^2, y^2, xy} ----
    for (int i = tid; i < IH * TW; i += 256) {
        int r = i >> 6;        // TW == 64
        int c = i & 63;
        float a0 = 0.f, a1 = 0.f, a2 = 0.f, a3 = 0.f, a4 = 0.f;
        int base = r * SSTRIDE + c;
        #pragma unroll
        for (int k = 0; k < KW; ++k) {
            float x = sx[base + k];
            float y = sy[base + k];
            float g = gw.g[k];
            float gx = g * x, gy = g * y;
            a0 += gx;
            a1 += gy;
            a2 = fmaf(gx, x, a2);
            a3 = fmaf(gy, y, a3);
            a4 = fmaf(gx, y, a4);
        }
        hb[0 * (IH * TW) + i] = a0;
        hb[1 * (IH * TW) + i] = a1;
        hb[2 * (IH * TW) + i] = a2;
        hb[3 * (IH * TW) + i] = a3;
        hb[4 * (IH * TW) + i] = a4;
    }
    __syncthreads();

    // ---- Stage C: vertical blur + SSIM map + local sum ----
    const float C1 = 1e-4f;   // 0.01^2
    const float C2 = 9e-4f;   // 0.03^2
    float lsum = 0.f;
    for (int i = tid; i < TH * TW; i += 256) {
        int r = i >> 6;
        int c = i & 63;
        float b0 = 0.f, b1 = 0.f, b2 = 0.f, b3 = 0.f, b4 = 0.f;
        #pragma unroll
        for (int k = 0; k < KW; ++k) {
            int hbase = (r + k) * TW + c;
            float g = gw.g[k];
            b0 = fmaf(g, hb[0 * (IH * TW) + hbase], b0);
            b1 = fmaf(g, hb[1 * (IH * TW) + hbase], b1);
            b2 = fmaf(g, hb[2 * (IH * TW) + hbase], b2);
            b3 = fmaf(g, hb[3 * (IH * TW) + hbase], b3);
            b4 = fmaf(g, hb[4 * (IH * TW) + hbase], b4);
        }
        float mu1 = b0, mu2 = b1;
        float mu1s = mu1 * mu1, mu2s = mu2 * mu2, mu12 = mu1 * mu2;
        float s1 = b2 - mu1s, s2 = b3 - mu2s, s12 = b4 - mu12;
        float num = (2.f * mu12 + C1) * (2.f * s12 + C2);
        float den = (mu1s + mu2s + C1) * (s1 + s2 + C2);
        lsum += num / den;
    }

    // ---- block reduction, then one atomic per block ----
    for (int off = 32; off > 0; off >>= 1)
        lsum += __shfl_down(lsum, off, 64);
    __shared__ float wsum[4];
    const int wid  = tid >> 6;
    const int lane = tid & 63;
    if (lane == 0) wsum[wid] = lsum;
    __syncthreads();
    if (tid == 0) {
        float bsum = wsum[0] + wsum[1] + wsum[2] + wsum[3];
        const float invN = 1.0f / (float)((size_t)NPLANES * HH * WW);
        atomicAdd(out, -bsum * invN);
    }
}

extern "C" void kernel_launch(void* const* d_in, const int* in_sizes, int n_in,
                              void* d_out, int out_size, void* d_ws, size_t ws_size,
                              hipStream_t stream) {
    const float* img = (const float*)d_in[0];
    const float* tgt = (const float*)d_in[1];
    float* out = (float*)d_out;

    // Gaussian window: computed in double, normalized, cast to fp32
    // (matches reference fp64 -> fp32 path).
    GaussW gw;
    double g[KW], s = 0.0;
    for (int i = 0; i < KW; ++i) {
        double d = (double)(i - KW / 2);
        g[i] = exp(-(d * d) / (2.0 * 1.5 * 1.5));
        s += g[i];
    }
    for (int i = 0; i < KW; ++i) gw.g[i] = (float)(g[i] / s);

    ssim_init_out<<<1, 1, 0, stream>>>(out);

    dim3 grid(WW / TW, HH / TH, NPLANES);  // 8 x 16 x 48
    ssim_fused<<<grid, 256, 0, stream>>>(img, tgt, out, gw);
}

// Round 2
// 122.078 us; speedup vs baseline: 1.3656x; 1.3656x over previous
//
#include <hip/hip_runtime.h>
#include <math.h>

// SSIM loss, fused single-pass, vectorized LDS (b128) + multi-output threads.
// Input: image, target fp32 [16,3,512,512]. Output: 1 scalar fp32.

#define HH 512
#define WW 512
#define NPLANES 48
#define TW 64                 // output tile width
#define TH 32                 // output tile height
#define RAD 5
#define IH (TH + 2*RAD)       // 42 staged rows
#define SSTR4 20              // staged row width in float4 units (80 floats: cols c0-8 .. c0+71)
#define KW 11

struct GaussW { float g[KW]; };

__global__ void ssim_init_out(float* out) { out[0] = 1.0f; }

__global__ __launch_bounds__(256, 2)
void ssim_fused(const float* __restrict__ img, const float* __restrict__ tgt,
                float* __restrict__ out, GaussW gw) {
    __shared__ alignas(16) float sx[IH * 80];
    __shared__ alignas(16) float sy[IH * 80];
    __shared__ alignas(16) float hb[5][IH][TW];   // horizontally blurred {x,y,x2,y2,xy}

    const int tid = threadIdx.x;
    const int p    = blockIdx.z;
    const int r0   = blockIdx.y * TH - RAD;
    const int c0m8 = blockIdx.x * TW - 8;         // leftmost staged col (multiple of 4)
    const float* ip = img + (size_t)p * (HH * WW);
    const float* tp = tgt + (size_t)p * (HH * WW);

    // ---- Stage A: stage halo region as aligned float4 (zero outside image) ----
    for (int i = tid; i < IH * SSTR4; i += 256) {
        int r  = i / SSTR4;
        int c4 = i - r * SSTR4;
        int gr = r0 + r;
        int gc = c0m8 + c4 * 4;                   // multiple of 4; fully in or fully out
        float4 vx = make_float4(0.f, 0.f, 0.f, 0.f);
        float4 vy = vx;
        if (gr >= 0 && gr < HH && gc >= 0 && gc <= WW - 4) {
            const size_t o = (size_t)gr * WW + gc;
            vx = *(const float4*)(ip + o);
            vy = *(const float4*)(tp + o);
        }
        ((float4*)sx)[i] = vx;
        ((float4*)sy)[i] = vy;
    }
    __syncthreads();

    // ---- Stage B: horizontal blur of {x,y,x2,y2,xy}; 4 outputs/thread ----
    for (int i = tid; i < IH * 16; i += 256) {
        int r  = i >> 4;
        int cg = i & 15;                          // float4-group of output cols
        const float4* sx4 = (const float4*)sx + r * SSTR4 + cg;
        const float4* sy4 = (const float4*)sy + r * SSTR4 + cg;
        float fx[20], fy[20];
        #pragma unroll
        for (int t = 0; t < 5; ++t) {
            float4 a = sx4[t];
            fx[4*t+0] = a.x; fx[4*t+1] = a.y; fx[4*t+2] = a.z; fx[4*t+3] = a.w;
            float4 b = sy4[t];
            fy[4*t+0] = b.x; fy[4*t+1] = b.y; fy[4*t+2] = b.z; fy[4*t+3] = b.w;
        }
        // products for the 14 inputs the 4 outputs touch (fx indices 3..16)
        float x2[14], y2[14], xy[14];
        #pragma unroll
        for (int t = 0; t < 14; ++t) {
            float xv = fx[t + 3], yv = fy[t + 3];
            x2[t] = xv * xv; y2[t] = yv * yv; xy[t] = xv * yv;
        }
        float a0[4] = {0,0,0,0}, a1[4] = {0,0,0,0}, a2[4] = {0,0,0,0},
              a3[4] = {0,0,0,0}, a4[4] = {0,0,0,0};
        #pragma unroll
        for (int k = 0; k < KW; ++k) {
            float g = gw.g[k];
            #pragma unroll
            for (int j = 0; j < 4; ++j) {
                a0[j] = fmaf(g, fx[3 + j + k], a0[j]);
                a1[j] = fmaf(g, fy[3 + j + k], a1[j]);
                a2[j] = fmaf(g, x2[j + k],     a2[j]);
                a3[j] = fmaf(g, y2[j + k],     a3[j]);
                a4[j] = fmaf(g, xy[j + k],     a4[j]);
            }
        }
        ((float4*)&hb[0][r][0])[cg] = make_float4(a0[0], a0[1], a0[2], a0[3]);
        ((float4*)&hb[1][r][0])[cg] = make_float4(a1[0], a1[1], a1[2], a1[3]);
        ((float4*)&hb[2][r][0])[cg] = make_float4(a2[0], a2[1], a2[2], a2[3]);
        ((float4*)&hb[3][r][0])[cg] = make_float4(a3[0], a3[1], a3[2], a3[3]);
        ((float4*)&hb[4][r][0])[cg] = make_float4(a4[0], a4[1], a4[2], a4[3]);
    }
    __syncthreads();

    // ---- Stage C: vertical blur + SSIM, 4x4 patch per thread (128 active) ----
    const float C1 = 1e-4f;   // 0.01^2
    const float C2 = 9e-4f;   // 0.03^2
    float lsum = 0.f;
    if (tid < 128) {
        int cg = tid & 15;                        // col group (4 cols)
        int rg = tid >> 4;                        // row group (4 rows), 0..7
        float acc[5][4][4];
        #pragma unroll
        for (int q = 0; q < 5; ++q)
            #pragma unroll
            for (int a = 0; a < 4; ++a)
                #pragma unroll
                for (int b = 0; b < 4; ++b) acc[q][a][b] = 0.f;

        #pragma unroll
        for (int kr = 0; kr < 14; ++kr) {
            int row = rg * 4 + kr;
            float4 v[5];
            #pragma unroll
            for (int q = 0; q < 5; ++q)
                v[q] = ((const float4*)&hb[q][row][0])[cg];
            #pragma unroll
            for (int ro = 0; ro < 4; ++ro) {
                int k = kr - ro;
                if (k >= 0 && k < KW) {
                    float g = gw.g[k];
                    #pragma unroll
                    for (int q = 0; q < 5; ++q) {
                        acc[q][ro][0] = fmaf(g, v[q].x, acc[q][ro][0]);
                        acc[q][ro][1] = fmaf(g, v[q].y, acc[q][ro][1]);
                        acc[q][ro][2] = fmaf(g, v[q].z, acc[q][ro][2]);
                        acc[q][ro][3] = fmaf(g, v[q].w, acc[q][ro][3]);
                    }
                }
            }
        }
        #pragma unroll
        for (int ro = 0; ro < 4; ++ro) {
            #pragma unroll
            for (int co = 0; co < 4; ++co) {
                float mu1 = acc[0][ro][co], mu2 = acc[1][ro][co];
                float mu1s = mu1 * mu1, mu2s = mu2 * mu2, mu12 = mu1 * mu2;
                float s1  = acc[2][ro][co] - mu1s;
                float s2  = acc[3][ro][co] - mu2s;
                float s12 = acc[4][ro][co] - mu12;
                float num = (2.f * mu12 + C1) * (2.f * s12 + C2);
                float den = (mu1s + mu2s + C1) * (s1 + s2 + C2);
                lsum += num / den;
            }
        }
    }

    // ---- block reduction, one atomic per block ----
    for (int off = 32; off > 0; off >>= 1)
        lsum += __shfl_down(lsum, off, 64);
    __shared__ float wsum[4];
    const int wid  = tid >> 6;
    const int lane = tid & 63;
    if (lane == 0) wsum[wid] = lsum;
    __syncthreads();
    if (tid == 0) {
        float bsum = wsum[0] + wsum[1] + wsum[2] + wsum[3];
        const float invN = 1.0f / (float)((size_t)NPLANES * HH * WW);
        atomicAdd(out, -bsum * invN);
    }
}

extern "C" void kernel_launch(void* const* d_in, const int* in_sizes, int n_in,
                              void* d_out, int out_size, void* d_ws, size_t ws_size,
                              hipStream_t stream) {
    const float* img = (const float*)d_in[0];
    const float* tgt = (const float*)d_in[1];
    float* out = (float*)d_out;

    GaussW gw;
    double g[KW], s = 0.0;
    for (int i = 0; i < KW; ++i) {
        double d = (double)(i - KW / 2);
        g[i] = exp(-(d * d) / (2.0 * 1.5 * 1.5));
        s += g[i];
    }
    for (int i = 0; i < KW; ++i) gw.g[i] = (float)(g[i] / s);

    ssim_init_out<<<1, 1, 0, stream>>>(out);

    dim3 grid(WW / TW, HH / TH, NPLANES);  // 8 x 16 x 48
    ssim_fused<<<grid, 256, 0, stream>>>(img, tgt, out, gw);
}

// Round 3
// 105.116 us; speedup vs baseline: 1.5859x; 1.1614x over previous
//
#include <hip/hip_runtime.h>
#include <math.h>

// SSIM loss, fused single-pass.
// Stage AB: h-blur of {x, y, x^2+y^2, xy} read directly from global (L1) -> LDS.
// Stage C : v-blur + SSIM map + reduction. 4 planes (s1+s2 only used summed).
// Input: image, target fp32 [16,3,512,512]. Output: 1 scalar fp32.

#define HH 512
#define WW 512
#define NPLANES 48
#define TW 64                 // output tile width
#define TH 32                 // output tile height
#define RAD 5
#define IH (TH + 2*RAD)       // 42 staged rows
#define HBS 68                // hb row stride (floats); 68%32=4 -> rows hit distinct banks
#define KW 11

struct GaussW { float g[KW]; };

__global__ void ssim_init_out(float* out) { out[0] = 1.0f; }

__global__ __launch_bounds__(256, 3)
void ssim_fused(const float* __restrict__ img, const float* __restrict__ tgt,
                float* __restrict__ out, GaussW gw) {
    __shared__ alignas(16) float hb[4][IH][HBS];   // {x, y, x2+y2, xy} h-blurred

    const int tid  = threadIdx.x;
    const int p    = blockIdx.z;
    const int r0   = blockIdx.y * TH - RAD;
    const int c0m8 = blockIdx.x * TW - 8;          // leftmost read col (multiple of 4)
    const float* ip = img + (size_t)p * (HH * WW);
    const float* tp = tgt + (size_t)p * (HH * WW);

    // ---- Stage AB: global -> h-blur -> hb (LDS). 4 output cols per item ----
    for (int i = tid; i < IH * 16; i += 256) {
        int r  = i >> 4;
        int cg = i & 15;
        int gr = r0 + r;
        bool rok = (gr >= 0) && (gr < HH);
        const float* xrow = ip + (size_t)gr * WW;
        const float* yrow = tp + (size_t)gr * WW;
        float fx[20], fy[20];
        #pragma unroll
        for (int t = 0; t < 5; ++t) {
            int gc = c0m8 + 4 * (cg + t);
            float4 a = make_float4(0.f, 0.f, 0.f, 0.f), b = a;
            if (rok && gc >= 0 && gc <= WW - 4) {
                a = *(const float4*)(xrow + gc);
                b = *(const float4*)(yrow + gc);
            }
            fx[4*t+0] = a.x; fx[4*t+1] = a.y; fx[4*t+2] = a.z; fx[4*t+3] = a.w;
            fy[4*t+0] = b.x; fy[4*t+1] = b.y; fy[4*t+2] = b.z; fy[4*t+3] = b.w;
        }
        float ss[14], xy[14];
        #pragma unroll
        for (int t = 0; t < 14; ++t) {
            float xv = fx[t + 3], yv = fy[t + 3];
            ss[t] = fmaf(xv, xv, yv * yv);   // x^2 + y^2
            xy[t] = xv * yv;
        }
        float a0[4] = {0,0,0,0}, a1[4] = {0,0,0,0},
              a2[4] = {0,0,0,0}, a3[4] = {0,0,0,0};
        #pragma unroll
        for (int k = 0; k < KW; ++k) {
            float g = gw.g[k];
            #pragma unroll
            for (int j = 0; j < 4; ++j) {
                a0[j] = fmaf(g, fx[3 + j + k], a0[j]);
                a1[j] = fmaf(g, fy[3 + j + k], a1[j]);
                a2[j] = fmaf(g, ss[j + k],    a2[j]);
                a3[j] = fmaf(g, xy[j + k],    a3[j]);
            }
        }
        ((float4*)&hb[0][r][0])[cg] = make_float4(a0[0], a0[1], a0[2], a0[3]);
        ((float4*)&hb[1][r][0])[cg] = make_float4(a1[0], a1[1], a1[2], a1[3]);
        ((float4*)&hb[2][r][0])[cg] = make_float4(a2[0], a2[1], a2[2], a2[3]);
        ((float4*)&hb[3][r][0])[cg] = make_float4(a3[0], a3[1], a3[2], a3[3]);
    }
    __syncthreads();

    // ---- Stage C: v-blur + SSIM; 2 rows x 4 cols per thread (all 256) ----
    const float C1 = 1e-4f;   // 0.01^2
    const float C2 = 9e-4f;   // 0.03^2
    const int cg = tid & 15;
    const int rg = tid >> 4;                 // 0..15 -> output rows 2rg, 2rg+1
    float acc[4][2][4];
    #pragma unroll
    for (int q = 0; q < 4; ++q)
        #pragma unroll
        for (int a = 0; a < 2; ++a)
            #pragma unroll
            for (int b = 0; b < 4; ++b) acc[q][a][b] = 0.f;

    #pragma unroll
    for (int kr = 0; kr < 12; ++kr) {
        int row = rg * 2 + kr;
        float4 v0 = ((const float4*)&hb[0][row][0])[cg];
        float4 v1 = ((const float4*)&hb[1][row][0])[cg];
        float4 v2 = ((const float4*)&hb[2][row][0])[cg];
        float4 v3 = ((const float4*)&hb[3][row][0])[cg];
        #pragma unroll
        for (int ro = 0; ro < 2; ++ro) {
            int k = kr - ro;
            if (k >= 0 && k < KW) {
                float g = gw.g[k];
                acc[0][ro][0] = fmaf(g, v0.x, acc[0][ro][0]);
                acc[0][ro][1] = fmaf(g, v0.y, acc[0][ro][1]);
                acc[0][ro][2] = fmaf(g, v0.z, acc[0][ro][2]);
                acc[0][ro][3] = fmaf(g, v0.w, acc[0][ro][3]);
                acc[1][ro][0] = fmaf(g, v1.x, acc[1][ro][0]);
                acc[1][ro][1] = fmaf(g, v1.y, acc[1][ro][1]);
                acc[1][ro][2] = fmaf(g, v1.z, acc[1][ro][2]);
                acc[1][ro][3] = fmaf(g, v1.w, acc[1][ro][3]);
                acc[2][ro][0] = fmaf(g, v2.x, acc[2][ro][0]);
                acc[2][ro][1] = fmaf(g, v2.y, acc[2][ro][1]);
                acc[2][ro][2] = fmaf(g, v2.z, acc[2][ro][2]);
                acc[2][ro][3] = fmaf(g, v2.w, acc[2][ro][3]);
                acc[3][ro][0] = fmaf(g, v3.x, acc[3][ro][0]);
                acc[3][ro][1] = fmaf(g, v3.y, acc[3][ro][1]);
                acc[3][ro][2] = fmaf(g, v3.z, acc[3][ro][2]);
                acc[3][ro][3] = fmaf(g, v3.w, acc[3][ro][3]);
            }
        }
    }
    float lsum = 0.f;
    #pragma unroll
    for (int ro = 0; ro < 2; ++ro) {
        #pragma unroll
        for (int co = 0; co < 4; ++co) {
            float mu1 = acc[0][ro][co], mu2 = acc[1][ro][co];
            float mu1s = mu1 * mu1, mu2s = mu2 * mu2, mu12 = mu1 * mu2;
            float ssum = acc[2][ro][co] - mu1s - mu2s;   // s1 + s2
            float s12  = acc[3][ro][co] - mu12;
            float num = (2.f * mu12 + C1) * (2.f * s12 + C2);
            float den = (mu1s + mu2s + C1) * (ssum + C2);
            lsum += num / den;
        }
    }

    // ---- block reduction, one atomic per block ----
    for (int off = 32; off > 0; off >>= 1)
        lsum += __shfl_down(lsum, off, 64);
    __shared__ float wsum[4];
    const int wid  = tid >> 6;
    const int lane = tid & 63;
    if (lane == 0) wsum[wid] = lsum;
    __syncthreads();
    if (tid == 0) {
        float bsum = wsum[0] + wsum[1] + wsum[2] + wsum[3];
        const float invN = 1.0f / (float)((size_t)NPLANES * HH * WW);
        atomicAdd(out, -bsum * invN);
    }
}

extern "C" void kernel_launch(void* const* d_in, const int* in_sizes, int n_in,
                              void* d_out, int out_size, void* d_ws, size_t ws_size,
                              hipStream_t stream) {
    const float* img = (const float*)d_in[0];
    const float* tgt = (const float*)d_in[1];
    float* out = (float*)d_out;

    GaussW gw;
    double g[KW], s = 0.0;
    for (int i = 0; i < KW; ++i) {
        double d = (double)(i - KW / 2);
        g[i] = exp(-(d * d) / (2.0 * 1.5 * 1.5));
        s += g[i];
    }
    for (int i = 0; i < KW; ++i) gw.g[i] = (float)(g[i] / s);

    ssim_init_out<<<1, 1, 0, stream>>>(out);

    dim3 grid(WW / TW, HH / TH, NPLANES);  // 8 x 16 x 48
    ssim_fused<<<grid, 256, 0, stream>>>(img, tgt, out, gw);
}